// Round 3
// baseline (310.411 us; speedup 1.0000x reference)
//
#include <hip/hip_runtime.h>
#include <stdint.h>

#define N_NODES 100000
#define N_EDGES 1000000
#define NBUCK 196   // ceil(N_NODES / 512)
#define CAP 6656    // per-bucket part capacity; counts ~ Poisson(5120), +21 sigma

typedef __attribute__((ext_vector_type(8))) __bf16 bf16x8;
typedef __attribute__((ext_vector_type(4))) float f32x4;

// ---------- bf16 helpers ----------
static __device__ __forceinline__ float bf2f(unsigned short u) {
    return __uint_as_float(((unsigned int)u) << 16);
}
static __device__ __forceinline__ unsigned short f2bf(float f) {
    unsigned int u = __float_as_uint(f);
    unsigned int r = (u + 0x7FFFu + ((u >> 16) & 1u)) >> 16;  // RNE
    return (unsigned short)r;
}
// pack 8 f32 -> 8 bf16, one 16B store
static __device__ __forceinline__ void st8_half(unsigned short* p, const float* f) {
    int4 u;
    u.x = (int)(((unsigned)f2bf(f[0])) | (((unsigned)f2bf(f[1])) << 16));
    u.y = (int)(((unsigned)f2bf(f[2])) | (((unsigned)f2bf(f[3])) << 16));
    u.z = (int)(((unsigned)f2bf(f[4])) | (((unsigned)f2bf(f[5])) << 16));
    u.w = (int)(((unsigned)f2bf(f[6])) | (((unsigned)f2bf(f[7])) << 16));
    *(int4*)p = u;
}

// ---------- dynamic-dtype external loads (flag: 1 = bf16 memory, 0 = f32) ----------
static __device__ __forceinline__ float ldf(const void* p, size_t i, int bf) {
    return bf ? bf2f(((const unsigned short*)p)[i]) : ((const float*)p)[i];
}

// ---------- dtype probe + cursor init ----------
__global__ __launch_bounds__(256) void detect_kernel(const unsigned short* __restrict__ xs,
                                                     int* __restrict__ flag,
                                                     int* __restrict__ bcursor) {
    __shared__ int sz;
    if (threadIdx.x == 0) sz = 0;
    __syncthreads();
    int z = 0;
    for (int i = threadIdx.x; i < 1024; i += 256) {
        float av = fabsf(bf2f(xs[2 * i]));
        if (!(av <= 1048576.0f) || (av != 0.0f && av < 9.5367431640625e-07f)) z++;
    }
    atomicAdd(&sz, z);
    if (threadIdx.x < NBUCK) bcursor[threadIdx.x] = threadIdx.x * CAP;
    __syncthreads();
    if (threadIdx.x == 0) *flag = (sz > 256) ? 0 : 1;
}

// ---------- partition edges into fixed-capacity bucket regions ----------
// rec = {src | dst_local<<17, val_bits}; region b = part[b*CAP ...); bucket = dst>>9
__global__ __launch_bounds__(256) void part_kernel(const int* __restrict__ src,
                                                   const int* __restrict__ dst,
                                                   const void* __restrict__ val,
                                                   int* __restrict__ bcursor,
                                                   int2* __restrict__ part,
                                                   const int* __restrict__ flagp) {
    __shared__ int cnt[NBUCK];
    __shared__ int base[NBUCK];
    const int bf = *flagp;
    const int tid = threadIdx.x;
    const int e0 = blockIdx.x * 2048;
    for (int i = tid; i < NBUCK; i += 256) cnt[i] = 0;
    __syncthreads();
    int rank[8], bkt[8], pk[8], vb[8];
#pragma unroll
    for (int i = 0; i < 8; ++i) {
        int e = e0 + i * 256 + tid;
        bkt[i] = -1;
        if (e < N_EDGES) {
            int d = dst[e];
            int b = d >> 9;
            bkt[i] = b;
            pk[i] = src[e] | ((d & 511) << 17);
            vb[i] = __float_as_int(ldf(val, e, bf));
            rank[i] = atomicAdd(&cnt[b], 1);
        }
    }
    __syncthreads();
    for (int i = tid; i < NBUCK; i += 256) {
        int c = cnt[i];
        base[i] = c ? atomicAdd(&bcursor[i], c) : 0;
    }
    __syncthreads();
#pragma unroll
    for (int i = 0; i < 8; ++i) {
        if (bkt[i] >= 0) part[(size_t)base[bkt[i]] + rank[i]] = make_int2(pk[i], vb[i]);
    }
}

// ---------- place: per-bucket (512 rows) histogram+scan, compact csr_rec + row_start ----------
// csr_rec keeps the FULL key (src | dst_local<<17) so gathers can recover the row.
__global__ __launch_bounds__(512) void place_kernel(const int* __restrict__ bcursor,
                                                    const int2* __restrict__ part,
                                                    int* __restrict__ row_start,
                                                    int2* __restrict__ csr_rec) {
    __shared__ int cnt[512];
    __shared__ int sums[512];
    __shared__ int sh_s, sh_cnt, sh_total;
    const int tid = threadIdx.x;
    const int b = blockIdx.x;
    const int row0 = b << 9;
    const int nrows = min(512, N_NODES - row0);

    // bucket-count exclusive prefix over 196 buckets (redundant per block, trivial)
    if (tid < 256) sums[tid] = (tid < NBUCK) ? (bcursor[tid] - tid * CAP) : 0;
    __syncthreads();
    for (int off = 1; off < 256; off <<= 1) {
        int t = 0;
        if (tid < 256 && tid >= off) t = sums[tid - off];
        __syncthreads();
        if (tid < 256 && tid >= off) sums[tid] += t;
        __syncthreads();
    }
    if (tid == 0) {
        sh_s = (b > 0) ? sums[b - 1] : 0;
        sh_cnt = bcursor[b] - b * CAP;
        sh_total = sums[NBUCK - 1];
    }
    __syncthreads();
    const int s = sh_s;          // global csr_rec start of this bucket
    const int cb = sh_cnt;       // edges in this bucket
    const int ps = b * CAP;      // part region start
    const int total = sh_total;

    cnt[tid] = 0;
    __syncthreads();
    for (int j = tid; j < cb; j += 512) {
        unsigned p = (unsigned)part[ps + j].x;
        atomicAdd(&cnt[p >> 17], 1);
    }
    __syncthreads();
    int own = cnt[tid];
    sums[tid] = own;
    __syncthreads();
    for (int off = 1; off < 512; off <<= 1) {
        int t = 0;
        if (tid >= off) t = sums[tid - off];
        __syncthreads();
        if (tid >= off) sums[tid] += t;
        __syncthreads();
    }
    int excl = sums[tid] - own;
    cnt[tid] = s + excl;              // running cursor (global position)
    if (tid < nrows) row_start[row0 + tid] = s + excl;
    if (b == NBUCK - 1 && tid == 0) row_start[N_NODES] = total;
    __syncthreads();
    for (int j = tid; j < cb; j += 512) {
        int2 r = part[ps + j];
        unsigned p = (unsigned)r.x;
        int pos = atomicAdd(&cnt[p >> 17], 1);
        csr_rec[pos] = make_int2((int)p, r.y);   // keep dst_local bits
    }
}

// ---------- edge-segmented gather: uniform segments, LDS f32 atomic flush ----------
// RS = support row stride (shorts); RMASK = row-in-tile mask; AST = agg row stride (f32).
// Each (group of lanes) walks a contiguous slice [s,e) of the tile's edge list,
// accumulating its current row in registers; flushes to LDS on row change.
template <int RS, int RMASK, int AST>
static __device__ __forceinline__ void seg_gather(const unsigned short* __restrict__ supc,
                                                  const int2* __restrict__ csr_rec,
                                                  int s, int e,
                                                  float* __restrict__ aggc /* &aggf[0] + cc*8 */) {
    if (s >= e) return;
    int2 r[8];
#pragma unroll
    for (int t = 0; t < 8; ++t) r[t] = csr_rec[min(s + t, e - 1)];
    int cur = (r[0].x >> 17) & RMASK;
    float a[8] = {0.f, 0.f, 0.f, 0.f, 0.f, 0.f, 0.f, 0.f};
    for (int j = s; j < e; j += 8) {
        int4 sp[8];
#pragma unroll
        for (int t = 0; t < 8; ++t)
            sp[t] = *(const int4*)(supc + (size_t)(r[t].x & 0x1FFFF) * RS);
        float wv[8];
        int rw[8];
#pragma unroll
        for (int t = 0; t < 8; ++t) {
            wv[t] = (j + t < e) ? __int_as_float(r[t].y) : 0.0f;
            rw[t] = (r[t].x >> 17) & RMASK;
        }
        int jn = j + 8;
        if (jn < e) {
#pragma unroll
            for (int t = 0; t < 8; ++t) r[t] = csr_rec[min(jn + t, e - 1)];
        }
#pragma unroll
        for (int t = 0; t < 8; ++t) {
            if (rw[t] != cur) {
#pragma unroll
                for (int c = 0; c < 8; ++c) atomicAdd(aggc + cur * AST + c, a[c]);
#pragma unroll
                for (int c = 0; c < 8; ++c) a[c] = 0.0f;
                cur = rw[t];
            }
            float w = wv[t];
            int q[4] = {sp[t].x, sp[t].y, sp[t].z, sp[t].w};
#pragma unroll
            for (int c = 0; c < 4; ++c) {
                float flo = __uint_as_float(((unsigned)q[c]) << 16);
                float fhi = __uint_as_float(((unsigned)q[c]) & 0xffff0000u);
                a[2 * c]     += w * flo;
                a[2 * c + 1] += w * fhi;
            }
        }
    }
#pragma unroll
    for (int c = 0; c < 8; ++c) atomicAdd(aggc + cur * AST + c, a[c]);
}

// ---------- MFMA GEMM (layer 1): one 64-row tile per block, A direct from global ----------
template <int K, int M, bool DYNIN>
__global__ __launch_bounds__(256, 8) void mgemm_kernel(const void* __restrict__ hv_,
                                                       const void* __restrict__ W,
                                                       unsigned short* __restrict__ out,
                                                       const int* __restrict__ flagp) {
    constexpr int KP = K + 8;
    constexpr int NC = M / 16;
    constexpr int NK = K / 32;

    __shared__ unsigned short wt[M][KP];  // W transposed

    const int bf = *flagp;
    const int tid = threadIdx.x;

    for (int i = tid; i < K * M; i += 256) {
        int k = i / M, m = i % M;
        wt[m][k] = f2bf(ldf(W, i, bf));
    }
    __syncthreads();

    const int lane = tid & 63;
    const int qd = lane >> 4;
    const int ln = lane & 15;
    const int wrow = (tid >> 6) * 16;
    const int tile = blockIdx.x;

    const int row = tile * 64 + wrow + ln;
    const bool ok = row < N_NODES;

    f32x4 acc[NC];
#pragma unroll
    for (int c = 0; c < NC; ++c) acc[c] = (f32x4){0.f, 0.f, 0.f, 0.f};

#pragma unroll
    for (int ks = 0; ks < NK; ++ks) {
        bf16x8 a;
        if (ok) {
            const size_t base = (size_t)row * K + ks * 32 + qd * 8;
            if (DYNIN && !bf) {
                const float* xp = (const float*)hv_ + base;
                float4 f0 = *(const float4*)xp;
                float4 f1 = *(const float4*)(xp + 4);
                ushort4 uu[2];
                uu[0].x = f2bf(f0.x); uu[0].y = f2bf(f0.y); uu[0].z = f2bf(f0.z); uu[0].w = f2bf(f0.w);
                uu[1].x = f2bf(f1.x); uu[1].y = f2bf(f1.y); uu[1].z = f2bf(f1.z); uu[1].w = f2bf(f1.w);
                a = *(const bf16x8*)uu;
            } else {
                a = *(const bf16x8*)((const unsigned short*)hv_ + base);
            }
        } else {
            a = (bf16x8)(__bf16)0.0f;
        }
#pragma unroll
        for (int c = 0; c < NC; ++c) {
            bf16x8 b = *(const bf16x8*)&wt[c * 16 + ln][ks * 32 + qd * 8];
            acc[c] = __builtin_amdgcn_mfma_f32_16x16x32_bf16(a, b, acc[c], 0, 0, 0);
        }
    }

#pragma unroll
    for (int c = 0; c < NC; ++c) {
#pragma unroll
        for (int r = 0; r < 4; ++r) {
            int orow = tile * 64 + wrow + qd * 4 + r;
            if (orow < N_NODES) out[(size_t)orow * M + c * 16 + ln] = f2bf(acc[c][r]);
        }
    }
}

// ---------- Fused: agg = relu(spmm(support)+bias); out = agg @ W  (K=64 fixed) ----------
// Edge-segmented gather into f32 LDS (atomics); bias+ReLU+cvt fused into the MFMA A-read.
template <int MOUT>
__global__ __launch_bounds__(256) void fused_kernel(const unsigned short* __restrict__ support,
                                                    const int* __restrict__ row_start,
                                                    const int2* __restrict__ csr_rec,
                                                    const void* __restrict__ bias,
                                                    const void* __restrict__ W,
                                                    unsigned short* __restrict__ out,
                                                    const int* __restrict__ flagp) {
    constexpr int K = 64, KP = 72;
    constexpr int AST = 68;             // agg row stride (f32): 2-way-max LDS banks
    constexpr int NC = MOUT / 16;

    __shared__ float aggf[64 * AST];    // 17.4 KB f32 accumulators
    __shared__ unsigned short wt[MOUT][KP];
    __shared__ float bb[K];

    const int bf = *flagp;
    const int tid = threadIdx.x;

    for (int i = tid; i < 64 * AST; i += 256) aggf[i] = 0.0f;
    for (int i = tid; i < K * MOUT; i += 256) {
        int k = i / MOUT, m = i % MOUT;
        wt[m][k] = f2bf(ldf(W, i, bf));
    }
    if (tid < K) bb[tid] = ldf(bias, tid, bf);
    __syncthreads();

    const int tile = blockIdx.x;
    const int S = row_start[min(tile * 64, N_NODES)];
    const int E = row_start[min(tile * 64 + 64, N_NODES)];
    const int grp = tid >> 3;   // 32 groups of 8 lanes
    const int cc = tid & 7;     // cols cc*8..cc*8+7
    const int len = E - S;
    const int s = S + ((len * grp) >> 5);
    const int e = S + ((len * (grp + 1)) >> 5);
    seg_gather<64, 63, AST>(support + cc * 8, csr_rec, s, e, aggf + cc * 8);
    __syncthreads();

    const int lane = tid & 63;
    const int qd = lane >> 4;
    const int ln = lane & 15;
    const int wrow = (tid >> 6) * 16;

    f32x4 macc[NC];
#pragma unroll
    for (int c = 0; c < NC; ++c) macc[c] = (f32x4){0.f, 0.f, 0.f, 0.f};
#pragma unroll
    for (int ks = 0; ks < 2; ++ks) {
        const int k0 = ks * 32 + qd * 8;
        const float* ap = &aggf[(wrow + ln) * AST + k0];
        float4 v0 = *(const float4*)ap;
        float4 v1 = *(const float4*)(ap + 4);
        float4 b0 = *(const float4*)&bb[k0];
        float4 b1 = *(const float4*)&bb[k0 + 4];
        int4 pa;
        pa.x = (int)(((unsigned)f2bf(fmaxf(v0.x + b0.x, 0.f))) |
                     (((unsigned)f2bf(fmaxf(v0.y + b0.y, 0.f))) << 16));
        pa.y = (int)(((unsigned)f2bf(fmaxf(v0.z + b0.z, 0.f))) |
                     (((unsigned)f2bf(fmaxf(v0.w + b0.w, 0.f))) << 16));
        pa.z = (int)(((unsigned)f2bf(fmaxf(v1.x + b1.x, 0.f))) |
                     (((unsigned)f2bf(fmaxf(v1.y + b1.y, 0.f))) << 16));
        pa.w = (int)(((unsigned)f2bf(fmaxf(v1.z + b1.z, 0.f))) |
                     (((unsigned)f2bf(fmaxf(v1.w + b1.w, 0.f))) << 16));
        union { int4 i; bf16x8 h; } ua;
        ua.i = pa;
        bf16x8 a = ua.h;
#pragma unroll
        for (int c = 0; c < NC; ++c) {
            bf16x8 b = *(const bf16x8*)&wt[c * 16 + ln][ks * 32 + qd * 8];
            macc[c] = __builtin_amdgcn_mfma_f32_16x16x32_bf16(a, b, macc[c], 0, 0, 0);
        }
    }

#pragma unroll
    for (int c = 0; c < NC; ++c) {
#pragma unroll
        for (int r = 0; r < 4; ++r) {
            int orow = tile * 64 + wrow + qd * 4 + r;
            if (orow < N_NODES) out[(size_t)orow * MOUT + c * 16 + ln] = f2bf(macc[c][r]);
        }
    }
}

// ---------- final SpMM (M=16): edge-segmented, 128-row tiles, 2-lane groups ----------
template <bool DYNOUT>
__global__ __launch_bounds__(256) void spmm16_kernel(const unsigned short* __restrict__ support,
                                                     const int* __restrict__ row_start,
                                                     const int2* __restrict__ csr_rec,
                                                     const void* __restrict__ bias,
                                                     void* __restrict__ out_,
                                                     const int* __restrict__ flagp) {
    constexpr int M = 16;
    constexpr int AST = 17;             // gcd(17,32)=1: conflict-light atomics
    __shared__ float aggf[128 * AST];   // 8.7 KB
    const int bf = *flagp;
    const int tid = threadIdx.x;
    for (int i = tid; i < 128 * AST; i += 256) aggf[i] = 0.0f;
    __syncthreads();

    const int b = blockIdx.x;
    const int S = row_start[min(b * 128, N_NODES)];
    const int E = row_start[min(b * 128 + 128, N_NODES)];
    const int grp = tid >> 1;   // 128 groups of 2 lanes
    const int cc = tid & 1;     // cols cc*8..cc*8+7
    const int len = E - S;
    const int s = S + ((len * grp) >> 7);
    const int e = S + ((len * (grp + 1)) >> 7);
    seg_gather<16, 127, AST>(support + cc * 8, csr_rec, s, e, aggf + cc * 8);
    __syncthreads();

    const int lrow = tid >> 1;
    const int half = tid & 1;
    const int row = b * 128 + lrow;
    if (row >= N_NODES) return;
    float o[8];
#pragma unroll
    for (int c = 0; c < 8; ++c)
        o[c] = aggf[lrow * AST + half * 8 + c] + ldf(bias, half * 8 + c, bf);
    if (DYNOUT && !bf) {
        float* op = (float*)out_ + (size_t)row * M + half * 8;
        *(float4*)op = make_float4(o[0], o[1], o[2], o[3]);
        *(float4*)(op + 4) = make_float4(o[4], o[5], o[6], o[7]);
    } else {
        st8_half((unsigned short*)out_ + (size_t)row * M + half * 8, o);
    }
}

extern "C" void kernel_launch(void* const* d_in, const int* in_sizes, int n_in,
                              void* d_out, int out_size, void* d_ws, size_t ws_size,
                              hipStream_t stream) {
    (void)in_sizes; (void)n_in; (void)out_size; (void)ws_size;
    const void* x  = d_in[0];
    const void* ev = d_in[1];
    const void* W1 = d_in[2];
    const void* b1 = d_in[3];
    const void* W2 = d_in[4];
    const void* b2 = d_in[5];
    const void* W3 = d_in[6];
    const void* b3 = d_in[7];
    const int* esrc = (const int*)d_in[8];
    const int* edst = (const int*)d_in[9];

    // workspace (~34 MB)
    char* ws = (char*)d_ws;
    size_t off = 0;
    auto alloc = [&](size_t bytes) -> void* {
        void* p = ws + off;
        off = (off + bytes + 255) & ~(size_t)255;
        return p;
    };
    unsigned short* A = (unsigned short*)alloc((size_t)N_NODES * 64 * 2);  // support1 / A3
    unsigned short* B = (unsigned short*)alloc((size_t)N_NODES * 64 * 2);  // A2
    int* row_start  = (int*)alloc((size_t)(N_NODES + 1) * 4);
    int* bcursor    = (int*)alloc(1024);
    int2* csr_rec   = (int2*)alloc((size_t)N_EDGES * 8);
    int* flagp      = (int*)alloc(256);
    // part[] (10.4 MB = 196*CAP*8) aliases A (12.8 MB): dead before mgemm1 writes A
    int2* part      = (int2*)A;

    // ---- dtype probe + cursor init ----
    detect_kernel<<<1, 256, 0, stream>>>((const unsigned short*)x, flagp, bcursor);

    // ---- CSR build: partition -> place (compact) ----
    part_kernel<<<(N_EDGES + 2047) / 2048, 256, 0, stream>>>(esrc, edst, ev, bcursor, part, flagp);
    place_kernel<<<NBUCK, 512, 0, stream>>>(bcursor, part, row_start, csr_rec);

    const int NT = (N_NODES + 63) / 64;  // 1563

    // ---- layer 1: A = x @ W1 ----
    mgemm_kernel<128, 64, true><<<NT, 256, 0, stream>>>(x, W1, A, flagp);
    // ---- layer 1 agg + layer 2 gemm fused: B = relu(spmm(A)+b1) @ W2 ----
    fused_kernel<64><<<NT, 256, 0, stream>>>(A, row_start, csr_rec, b1, W2, B, flagp);
    // ---- layer 2 agg + layer 3 gemm fused: A(=A3) = relu(spmm(B)+b2) @ W3 ----
    fused_kernel<16><<<NT, 256, 0, stream>>>(B, row_start, csr_rec, b2, W3, A, flagp);
    // ---- final aggregation: out = spmm(A3) + b3 ----
    spmm16_kernel<true><<<(N_NODES + 127) / 128, 256, 0, stream>>>(A, row_start, csr_rec, b3, d_out, flagp);
}

// Round 4
// 279.509 us; speedup vs baseline: 1.1106x; 1.1106x over previous
//
#include <hip/hip_runtime.h>
#include <stdint.h>

#define N_NODES 100000
#define N_EDGES 1000000
#define NBUCK 196   // ceil(N_NODES / 512)
#define CAP 6656    // per-bucket part capacity; counts ~ Poisson(5120), +21 sigma

typedef __attribute__((ext_vector_type(8))) __bf16 bf16x8;
typedef __attribute__((ext_vector_type(4))) float f32x4;

// ---------- bf16 helpers ----------
static __device__ __forceinline__ float bf2f(unsigned short u) {
    return __uint_as_float(((unsigned int)u) << 16);
}
static __device__ __forceinline__ unsigned short f2bf(float f) {
    unsigned int u = __float_as_uint(f);
    unsigned int r = (u + 0x7FFFu + ((u >> 16) & 1u)) >> 16;  // RNE
    return (unsigned short)r;
}
// pack 8 f32 -> 8 bf16, one 16B store
static __device__ __forceinline__ void st8_half(unsigned short* p, const float* f) {
    int4 u;
    u.x = (int)(((unsigned)f2bf(f[0])) | (((unsigned)f2bf(f[1])) << 16));
    u.y = (int)(((unsigned)f2bf(f[2])) | (((unsigned)f2bf(f[3])) << 16));
    u.z = (int)(((unsigned)f2bf(f[4])) | (((unsigned)f2bf(f[5])) << 16));
    u.w = (int)(((unsigned)f2bf(f[6])) | (((unsigned)f2bf(f[7])) << 16));
    *(int4*)p = u;
}

// ---------- dynamic-dtype external loads (flag: 1 = bf16 memory, 0 = f32) ----------
static __device__ __forceinline__ float ldf(const void* p, size_t i, int bf) {
    return bf ? bf2f(((const unsigned short*)p)[i]) : ((const float*)p)[i];
}

// ---------- dtype probe + cursor init ----------
__global__ __launch_bounds__(256) void detect_kernel(const unsigned short* __restrict__ xs,
                                                     int* __restrict__ flag,
                                                     int* __restrict__ bcursor) {
    __shared__ int sz;
    if (threadIdx.x == 0) sz = 0;
    __syncthreads();
    int z = 0;
    for (int i = threadIdx.x; i < 1024; i += 256) {
        float av = fabsf(bf2f(xs[2 * i]));
        if (!(av <= 1048576.0f) || (av != 0.0f && av < 9.5367431640625e-07f)) z++;
    }
    atomicAdd(&sz, z);
    if (threadIdx.x < NBUCK) bcursor[threadIdx.x] = threadIdx.x * CAP;
    __syncthreads();
    if (threadIdx.x == 0) *flag = (sz > 256) ? 0 : 1;
}

// ---------- partition edges into fixed-capacity bucket regions ----------
// rec = {src | dst_local<<17, val_bits}; region b = part[b*CAP ...); bucket = dst>>9
__global__ __launch_bounds__(256) void part_kernel(const int* __restrict__ src,
                                                   const int* __restrict__ dst,
                                                   const void* __restrict__ val,
                                                   int* __restrict__ bcursor,
                                                   int2* __restrict__ part,
                                                   const int* __restrict__ flagp) {
    __shared__ int cnt[NBUCK];
    __shared__ int base[NBUCK];
    const int bf = *flagp;
    const int tid = threadIdx.x;
    const int e0 = blockIdx.x * 2048;
    for (int i = tid; i < NBUCK; i += 256) cnt[i] = 0;
    __syncthreads();
    int rank[8], bkt[8], pk[8], vb[8];
#pragma unroll
    for (int i = 0; i < 8; ++i) {
        int e = e0 + i * 256 + tid;
        bkt[i] = -1;
        if (e < N_EDGES) {
            int d = dst[e];
            int b = d >> 9;
            bkt[i] = b;
            pk[i] = src[e] | ((d & 511) << 17);
            vb[i] = __float_as_int(ldf(val, e, bf));
            rank[i] = atomicAdd(&cnt[b], 1);
        }
    }
    __syncthreads();
    for (int i = tid; i < NBUCK; i += 256) {
        int c = cnt[i];
        base[i] = c ? atomicAdd(&bcursor[i], c) : 0;
    }
    __syncthreads();
#pragma unroll
    for (int i = 0; i < 8; ++i) {
        if (bkt[i] >= 0) part[(size_t)base[bkt[i]] + rank[i]] = make_int2(pk[i], vb[i]);
    }
}

// ---------- place: per-bucket (512 rows) histogram+scan, compact csr_rec + row_start ----------
// csr_rec keeps the FULL key (src | dst_local<<17) so gathers can recover the row.
__global__ __launch_bounds__(512) void place_kernel(const int* __restrict__ bcursor,
                                                    const int2* __restrict__ part,
                                                    int* __restrict__ row_start,
                                                    int2* __restrict__ csr_rec) {
    __shared__ int cnt[512];
    __shared__ int sums[512];
    __shared__ int sh_s, sh_cnt, sh_total;
    const int tid = threadIdx.x;
    const int b = blockIdx.x;
    const int row0 = b << 9;
    const int nrows = min(512, N_NODES - row0);

    // bucket-count exclusive prefix over 196 buckets (redundant per block, trivial)
    if (tid < 256) sums[tid] = (tid < NBUCK) ? (bcursor[tid] - tid * CAP) : 0;
    __syncthreads();
    for (int off = 1; off < 256; off <<= 1) {
        int t = 0;
        if (tid < 256 && tid >= off) t = sums[tid - off];
        __syncthreads();
        if (tid < 256 && tid >= off) sums[tid] += t;
        __syncthreads();
    }
    if (tid == 0) {
        sh_s = (b > 0) ? sums[b - 1] : 0;
        sh_cnt = bcursor[b] - b * CAP;
        sh_total = sums[NBUCK - 1];
    }
    __syncthreads();
    const int s = sh_s;          // global csr_rec start of this bucket
    const int cb = sh_cnt;       // edges in this bucket
    const int ps = b * CAP;      // part region start
    const int total = sh_total;

    cnt[tid] = 0;
    __syncthreads();
    for (int j = tid; j < cb; j += 512) {
        unsigned p = (unsigned)part[ps + j].x;
        atomicAdd(&cnt[p >> 17], 1);
    }
    __syncthreads();
    int own = cnt[tid];
    sums[tid] = own;
    __syncthreads();
    for (int off = 1; off < 512; off <<= 1) {
        int t = 0;
        if (tid >= off) t = sums[tid - off];
        __syncthreads();
        if (tid >= off) sums[tid] += t;
        __syncthreads();
    }
    int excl = sums[tid] - own;
    cnt[tid] = s + excl;              // running cursor (global position)
    if (tid < nrows) row_start[row0 + tid] = s + excl;
    if (b == NBUCK - 1 && tid == 0) row_start[N_NODES] = total;
    __syncthreads();
    for (int j = tid; j < cb; j += 512) {
        int2 r = part[ps + j];
        unsigned p = (unsigned)r.x;
        int pos = atomicAdd(&cnt[p >> 17], 1);
        csr_rec[pos] = make_int2((int)p, r.y);   // keep dst_local bits
    }
}

// ---------- MFMA GEMM (layer 1): one 64-row tile per block, A direct from global ----------
template <int K, int M, bool DYNIN>
__global__ __launch_bounds__(256, 8) void mgemm_kernel(const void* __restrict__ hv_,
                                                       const void* __restrict__ W,
                                                       unsigned short* __restrict__ out,
                                                       const int* __restrict__ flagp) {
    constexpr int KP = K + 8;
    constexpr int NC = M / 16;
    constexpr int NK = K / 32;

    __shared__ __align__(16) unsigned short wt[M][KP];  // W transposed

    const int bf = *flagp;
    const int tid = threadIdx.x;

    for (int i = tid; i < K * M; i += 256) {
        int k = i / M, m = i % M;
        wt[m][k] = f2bf(ldf(W, i, bf));
    }
    __syncthreads();

    const int lane = tid & 63;
    const int qd = lane >> 4;
    const int ln = lane & 15;
    const int wrow = (tid >> 6) * 16;
    const int tile = blockIdx.x;

    const int row = tile * 64 + wrow + ln;
    const bool ok = row < N_NODES;

    f32x4 acc[NC];
#pragma unroll
    for (int c = 0; c < NC; ++c) acc[c] = (f32x4){0.f, 0.f, 0.f, 0.f};

#pragma unroll
    for (int ks = 0; ks < NK; ++ks) {
        bf16x8 a;
        if (ok) {
            const size_t base = (size_t)row * K + ks * 32 + qd * 8;
            if (DYNIN && !bf) {
                const float* xp = (const float*)hv_ + base;
                float4 f0 = *(const float4*)xp;
                float4 f1 = *(const float4*)(xp + 4);
                ushort4 uu[2];
                uu[0].x = f2bf(f0.x); uu[0].y = f2bf(f0.y); uu[0].z = f2bf(f0.z); uu[0].w = f2bf(f0.w);
                uu[1].x = f2bf(f1.x); uu[1].y = f2bf(f1.y); uu[1].z = f2bf(f1.z); uu[1].w = f2bf(f1.w);
                a = *(const bf16x8*)uu;
            } else {
                a = *(const bf16x8*)((const unsigned short*)hv_ + base);
            }
        } else {
            a = (bf16x8)(__bf16)0.0f;
        }
#pragma unroll
        for (int c = 0; c < NC; ++c) {
            bf16x8 b = *(const bf16x8*)&wt[c * 16 + ln][ks * 32 + qd * 8];
            acc[c] = __builtin_amdgcn_mfma_f32_16x16x32_bf16(a, b, acc[c], 0, 0, 0);
        }
    }

#pragma unroll
    for (int c = 0; c < NC; ++c) {
#pragma unroll
        for (int r = 0; r < 4; ++r) {
            int orow = tile * 64 + wrow + qd * 4 + r;
            if (orow < N_NODES) out[(size_t)orow * M + c * 16 + ln] = f2bf(acc[c][r]);
        }
    }
}

// ---------- Gt swizzled offset: element (support-col c, edge-pos pos) ----------
// Stride 72 u16 per col-row; pos-blocks of 8 XOR'd by (c>>3) so the transposed
// 8x-b16 scatter writes spread across banks; b128 reads stay contiguous+aligned.
static __device__ __forceinline__ int gt_off(int c, int pos) {
    return c * 72 + ((((pos >> 3) ^ (c >> 3)) & 7) << 3) + (pos & 7);
}

// ---------- MFMA aggregation (+ optional fused GEMM) ----------
// Per 64-row dst tile: chunks of 64 edges. W-block[dst][pos] (bf16 hi+lo split)
// scattered into LDS, source rows gathered TRANSPOSED into Gt[col][pos], then
// dense MFMA acc += W * Gt^T accumulates the aggregation in f32 across chunks.
// FINAL: out = acc + bias (global store). else: agg = relu(acc+bias) -> agg @ W.
template <int COLS, int MOUT, bool FINAL, bool DYNOUT>
__global__ __launch_bounds__(256) void agg_kernel(const unsigned short* __restrict__ support,
                                                  const int* __restrict__ row_start,
                                                  const int2* __restrict__ csr_rec,
                                                  const void* __restrict__ bias,
                                                  const void* __restrict__ W,
                                                  void* __restrict__ out_,
                                                  const int* __restrict__ flagp) {
    constexpr int ST = 72;
    constexpr int NCA = COLS / 16;       // agg col tiles
    constexpr int NCO = MOUT / 16;       // gemm out col tiles
    constexpr int SPE = COLS / 8;        // 16B slots per edge
    constexpr int SLOTS = 64 * SPE;      // slots per chunk

    __shared__ __align__(16) unsigned short Wsc[2][64][ST];
    __shared__ __align__(16) unsigned short Gt[COLS * ST];
    __shared__ __align__(16) unsigned short wt[FINAL ? 16 : MOUT][ST];
    __shared__ float bb[COLS];

    const int bf = *flagp;
    const int tid = threadIdx.x;
    const int tile = blockIdx.x;

    // zero Wsc (once; per-chunk cleanup is done by unscatter)
    {
        int4 z = make_int4(0, 0, 0, 0);
        int4* wz = (int4*)&Wsc[0][0][0];
#pragma unroll 2
        for (int i = tid; i < 2 * 64 * ST / 8; i += 256) wz[i] = z;
    }
    if (!FINAL) {
        for (int i = tid; i < 64 * MOUT; i += 256) {
            int k = i / MOUT, m = i % MOUT;
            wt[m][k] = f2bf(ldf(W, i, bf));
        }
    }
    if (tid < COLS) bb[tid] = ldf(bias, tid, bf);

    const int S = row_start[min(tile * 64, N_NODES)];
    const int E = row_start[min(tile * 64 + 64, N_NODES)];
    __syncthreads();

    const int lane = tid & 63;
    const int qd = lane >> 4;
    const int ln = lane & 15;
    const int wrow = (tid >> 6) * 16;

    f32x4 acc[NCA];
#pragma unroll
    for (int c = 0; c < NCA; ++c) acc[c] = (f32x4){0.f, 0.f, 0.f, 0.f};

    int dl = -1;  // my scattered row (column tid of Wsc), for unscatter
    for (int e0 = S; e0 < E; e0 += 64) {
        // scatter edge weights (hi+lo bf16 split) into W-block column tid
        if (tid < 64) {
            int idx = e0 + tid;
            if (idx < E) {
                int2 r = csr_rec[idx];
                dl = (r.x >> 17) & 63;
                float w = __int_as_float(r.y);
                unsigned short wh = f2bf(w);
                Wsc[0][dl][tid] = wh;
                Wsc[1][dl][tid] = f2bf(w - bf2f(wh));
            } else {
                dl = -1;
            }
        }
        // gather 64 source rows, transposed into Gt[col][pos]
#pragma unroll
        for (int ss = 0; ss < SLOTS; ss += 256) {
            int slot = ss + tid;
            if (slot < SLOTS) {
                int pos = slot / SPE;
                int c8 = (slot % SPE) * 8;
                int2 r = csr_rec[min(e0 + pos, E - 1)];
                int src = r.x & 0x1FFFF;
                int4 g = *(const int4*)(support + (size_t)src * COLS + c8);
                const unsigned short* gp = (const unsigned short*)&g;
#pragma unroll
                for (int jj = 0; jj < 8; ++jj) Gt[gt_off(c8 + jj, pos)] = gp[jj];
            }
        }
        __syncthreads();
        // dense MFMA over the chunk: acc += Wh*G + Wl*G
#pragma unroll
        for (int ks = 0; ks < 2; ++ks) {
            const int k0 = ks * 32 + qd * 8;
            bf16x8 ah = *(const bf16x8*)&Wsc[0][wrow + ln][k0];
            bf16x8 al = *(const bf16x8*)&Wsc[1][wrow + ln][k0];
#pragma unroll
            for (int c = 0; c < NCA; ++c) {
                bf16x8 b = *(const bf16x8*)&Gt[gt_off(c * 16 + ln, k0)];
                acc[c] = __builtin_amdgcn_mfma_f32_16x16x32_bf16(ah, b, acc[c], 0, 0, 0);
                acc[c] = __builtin_amdgcn_mfma_f32_16x16x32_bf16(al, b, acc[c], 0, 0, 0);
            }
        }
        __syncthreads();
        // unscatter: re-zero only my element (same thread rewrites next chunk)
        if (dl >= 0) {
            Wsc[0][dl][tid] = 0;
            Wsc[1][dl][tid] = 0;
        }
    }

    if constexpr (FINAL) {
        // out = acc + bias   (COLS == 16, NCA == 1)
#pragma unroll
        for (int r = 0; r < 4; ++r) {
            int row = tile * 64 + wrow + qd * 4 + r;
            if (row < N_NODES) {
                float v = acc[0][r] + bb[ln];
                if (DYNOUT && !bf) ((float*)out_)[(size_t)row * 16 + ln] = v;
                else ((unsigned short*)out_)[(size_t)row * 16 + ln] = f2bf(v);
            }
        }
    } else {
        __syncthreads();  // all unscatters done before Wsc[0] is reused as agg
        unsigned short (*agg)[ST] = Wsc[0];
#pragma unroll
        for (int c = 0; c < NCA; ++c) {
#pragma unroll
            for (int r = 0; r < 4; ++r) {
                agg[wrow + qd * 4 + r][c * 16 + ln] =
                    f2bf(fmaxf(acc[c][r] + bb[c * 16 + ln], 0.f));
            }
        }
        __syncthreads();
        // GEMM: out = agg @ W   (K = COLS = 64)
        f32x4 macc[NCO];
#pragma unroll
        for (int c = 0; c < NCO; ++c) macc[c] = (f32x4){0.f, 0.f, 0.f, 0.f};
#pragma unroll
        for (int ks = 0; ks < 2; ++ks) {
            bf16x8 a = *(const bf16x8*)&agg[wrow + ln][ks * 32 + qd * 8];
#pragma unroll
            for (int c = 0; c < NCO; ++c) {
                bf16x8 b = *(const bf16x8*)&wt[c * 16 + ln][ks * 32 + qd * 8];
                macc[c] = __builtin_amdgcn_mfma_f32_16x16x32_bf16(a, b, macc[c], 0, 0, 0);
            }
        }
        unsigned short* outp = (unsigned short*)out_;
#pragma unroll
        for (int c = 0; c < NCO; ++c) {
#pragma unroll
            for (int r = 0; r < 4; ++r) {
                int orow = tile * 64 + wrow + qd * 4 + r;
                if (orow < N_NODES) outp[(size_t)orow * MOUT + c * 16 + ln] = f2bf(macc[c][r]);
            }
        }
    }
}

extern "C" void kernel_launch(void* const* d_in, const int* in_sizes, int n_in,
                              void* d_out, int out_size, void* d_ws, size_t ws_size,
                              hipStream_t stream) {
    (void)in_sizes; (void)n_in; (void)out_size; (void)ws_size;
    const void* x  = d_in[0];
    const void* ev = d_in[1];
    const void* W1 = d_in[2];
    const void* b1 = d_in[3];
    const void* W2 = d_in[4];
    const void* b2 = d_in[5];
    const void* W3 = d_in[6];
    const void* b3 = d_in[7];
    const int* esrc = (const int*)d_in[8];
    const int* edst = (const int*)d_in[9];

    // workspace (~34 MB)
    char* ws = (char*)d_ws;
    size_t off = 0;
    auto alloc = [&](size_t bytes) -> void* {
        void* p = ws + off;
        off = (off + bytes + 255) & ~(size_t)255;
        return p;
    };
    unsigned short* A = (unsigned short*)alloc((size_t)N_NODES * 64 * 2);  // support1 / A3
    unsigned short* B = (unsigned short*)alloc((size_t)N_NODES * 64 * 2);  // A2
    int* row_start  = (int*)alloc((size_t)(N_NODES + 1) * 4);
    int* bcursor    = (int*)alloc(1024);
    int2* csr_rec   = (int2*)alloc((size_t)N_EDGES * 8);
    int* flagp      = (int*)alloc(256);
    // part[] (10.4 MB = 196*CAP*8) aliases A (12.8 MB): dead before mgemm1 writes A
    int2* part      = (int2*)A;

    // ---- dtype probe + cursor init ----
    detect_kernel<<<1, 256, 0, stream>>>((const unsigned short*)x, flagp, bcursor);

    // ---- CSR build: partition -> place (compact) ----
    part_kernel<<<(N_EDGES + 2047) / 2048, 256, 0, stream>>>(esrc, edst, ev, bcursor, part, flagp);
    place_kernel<<<NBUCK, 512, 0, stream>>>(bcursor, part, row_start, csr_rec);

    const int NT = (N_NODES + 63) / 64;  // 1563

    // ---- layer 1: A = x @ W1 ----
    mgemm_kernel<128, 64, true><<<NT, 256, 0, stream>>>(x, W1, A, flagp);
    // ---- layer 1 agg + layer 2 gemm: B = relu(spmm(A)+b1) @ W2 ----
    agg_kernel<64, 64, false, false><<<NT, 256, 0, stream>>>(A, row_start, csr_rec, b1, W2, B, flagp);
    // ---- layer 2 agg + layer 3 gemm: A(=A3) = relu(spmm(B)+b2) @ W3 ----
    agg_kernel<64, 16, false, false><<<NT, 256, 0, stream>>>(B, row_start, csr_rec, b2, W3, A, flagp);
    // ---- final aggregation: out = spmm(A3) + b3 ----
    agg_kernel<16, 16, true, true><<<NT, 256, 0, stream>>>(A, row_start, csr_rec, b3, b3, d_out, flagp);
}

// Round 5
// 228.642 us; speedup vs baseline: 1.3576x; 1.2225x over previous
//
#include <hip/hip_runtime.h>
#include <stdint.h>

#define N_NODES 100000
#define N_EDGES 1000000
#define NBUCK 196   // ceil(N_NODES / 512)
#define CAP 6656    // per-bucket part capacity; counts ~ Poisson(5120), +21 sigma

typedef __attribute__((ext_vector_type(8))) __bf16 bf16x8;
typedef __attribute__((ext_vector_type(4))) float f32x4;

// ---------- bf16 helpers ----------
static __device__ __forceinline__ float bf2f(unsigned short u) {
    return __uint_as_float(((unsigned int)u) << 16);
}
static __device__ __forceinline__ unsigned short f2bf(float f) {
    unsigned int u = __float_as_uint(f);
    unsigned int r = (u + 0x7FFFu + ((u >> 16) & 1u)) >> 16;  // RNE
    return (unsigned short)r;
}
// pack 8 f32 -> 8 bf16, one 16B store
static __device__ __forceinline__ void st8_half(unsigned short* p, const float* f) {
    int4 u;
    u.x = (int)(((unsigned)f2bf(f[0])) | (((unsigned)f2bf(f[1])) << 16));
    u.y = (int)(((unsigned)f2bf(f[2])) | (((unsigned)f2bf(f[3])) << 16));
    u.z = (int)(((unsigned)f2bf(f[4])) | (((unsigned)f2bf(f[5])) << 16));
    u.w = (int)(((unsigned)f2bf(f[6])) | (((unsigned)f2bf(f[7])) << 16));
    *(int4*)p = u;
}

// ---------- dynamic-dtype external loads (flag: 1 = bf16 memory, 0 = f32) ----------
static __device__ __forceinline__ float ldf(const void* p, size_t i, int bf) {
    return bf ? bf2f(((const unsigned short*)p)[i]) : ((const float*)p)[i];
}

// ---------- dtype probe + cursor init ----------
__global__ __launch_bounds__(256) void detect_kernel(const unsigned short* __restrict__ xs,
                                                     int* __restrict__ flag,
                                                     int* __restrict__ bcursor) {
    __shared__ int sz;
    if (threadIdx.x == 0) sz = 0;
    __syncthreads();
    int z = 0;
    for (int i = threadIdx.x; i < 1024; i += 256) {
        float av = fabsf(bf2f(xs[2 * i]));
        if (!(av <= 1048576.0f) || (av != 0.0f && av < 9.5367431640625e-07f)) z++;
    }
    atomicAdd(&sz, z);
    if (threadIdx.x < NBUCK) bcursor[threadIdx.x] = threadIdx.x * CAP;
    __syncthreads();
    if (threadIdx.x == 0) *flag = (sz > 256) ? 0 : 1;
}

// ---------- partition edges into fixed-capacity bucket regions ----------
// rec = {src | dst_local<<17, val_bits}; region b = part[b*CAP ...); bucket = dst>>9
__global__ __launch_bounds__(256) void part_kernel(const int* __restrict__ src,
                                                   const int* __restrict__ dst,
                                                   const void* __restrict__ val,
                                                   int* __restrict__ bcursor,
                                                   int2* __restrict__ part,
                                                   const int* __restrict__ flagp) {
    __shared__ int cnt[NBUCK];
    __shared__ int base[NBUCK];
    const int bf = *flagp;
    const int tid = threadIdx.x;
    const int e0 = blockIdx.x * 2048;
    for (int i = tid; i < NBUCK; i += 256) cnt[i] = 0;
    __syncthreads();
    int rank[8], bkt[8], pk[8], vb[8];
#pragma unroll
    for (int i = 0; i < 8; ++i) {
        int e = e0 + i * 256 + tid;
        bkt[i] = -1;
        if (e < N_EDGES) {
            int d = dst[e];
            int b = d >> 9;
            bkt[i] = b;
            pk[i] = src[e] | ((d & 511) << 17);
            vb[i] = __float_as_int(ldf(val, e, bf));
            rank[i] = atomicAdd(&cnt[b], 1);
        }
    }
    __syncthreads();
    for (int i = tid; i < NBUCK; i += 256) {
        int c = cnt[i];
        base[i] = c ? atomicAdd(&bcursor[i], c) : 0;
    }
    __syncthreads();
#pragma unroll
    for (int i = 0; i < 8; ++i) {
        if (bkt[i] >= 0) part[(size_t)base[bkt[i]] + rank[i]] = make_int2(pk[i], vb[i]);
    }
}

// ---------- place: per-(row,src-slab) histogram+scan, compact csr_rec + row_start ----------
// Within each row, edges are ordered by src slab (src>>14, 7 slabs of 16K rows = 2MB).
// All co-resident gather blocks then sweep src slabs roughly in lockstep, so the
// active src window stays L2-resident per XCD (random L3 misses -> L2 hits).
__global__ __launch_bounds__(512) void place_kernel(const int* __restrict__ bcursor,
                                                    const int2* __restrict__ part,
                                                    int* __restrict__ row_start,
                                                    int2* __restrict__ csr_rec) {
    __shared__ int cnt2[4096];   // cursor per (row_local<<3 | slab)
    __shared__ int sums[512];
    __shared__ int sh_s, sh_cnt, sh_total;
    const int tid = threadIdx.x;
    const int b = blockIdx.x;
    const int row0 = b << 9;
    const int nrows = min(512, N_NODES - row0);

    // bucket-count exclusive prefix over 196 buckets (redundant per block, trivial)
    if (tid < 256) sums[tid] = (tid < NBUCK) ? (bcursor[tid] - tid * CAP) : 0;
    __syncthreads();
    for (int off = 1; off < 256; off <<= 1) {
        int t = 0;
        if (tid < 256 && tid >= off) t = sums[tid - off];
        __syncthreads();
        if (tid < 256 && tid >= off) sums[tid] += t;
        __syncthreads();
    }
    if (tid == 0) {
        sh_s = (b > 0) ? sums[b - 1] : 0;
        sh_cnt = bcursor[b] - b * CAP;
        sh_total = sums[NBUCK - 1];
    }
    __syncthreads();
    const int s = sh_s;          // global csr_rec start of this bucket
    const int cb = sh_cnt;       // edges in this bucket
    const int ps = b * CAP;      // part region start
    const int total = sh_total;

    for (int i = tid; i < 4096; i += 512) cnt2[i] = 0;
    __syncthreads();
    for (int j = tid; j < cb; j += 512) {
        unsigned p = (unsigned)part[ps + j].x;
        int key = (int)((p >> 17) << 3) | (int)((p & 0x1FFFFu) >> 14);
        atomicAdd(&cnt2[key], 1);
    }
    __syncthreads();
    // per-thread: row tid's 8 slab counts -> row sum; block scan; in-row exclusive
    int c8[8];
    int rs = 0;
#pragma unroll
    for (int k = 0; k < 8; ++k) { c8[k] = cnt2[tid * 8 + k]; rs += c8[k]; }
    sums[tid] = rs;
    __syncthreads();
    for (int off = 1; off < 512; off <<= 1) {
        int t = 0;
        if (tid >= off) t = sums[tid - off];
        __syncthreads();
        if (tid >= off) sums[tid] += t;
        __syncthreads();
    }
    int run = s + sums[tid] - rs;        // row-exclusive global start
    if (tid < nrows) row_start[row0 + tid] = run;
    if (b == NBUCK - 1 && tid == 0) row_start[N_NODES] = total;
#pragma unroll
    for (int k = 0; k < 8; ++k) { cnt2[tid * 8 + k] = run; run += c8[k]; }
    __syncthreads();
    for (int j = tid; j < cb; j += 512) {
        int2 r = part[ps + j];
        unsigned p = (unsigned)r.x;
        int key = (int)((p >> 17) << 3) | (int)((p & 0x1FFFFu) >> 14);
        int pos = atomicAdd(&cnt2[key], 1);
        csr_rec[pos] = make_int2((int)(p & 0x1FFFFu), r.y);
    }
}

// ---------- single-row gather: 8 bf16 cols per lane, chunk of 4 edges ----------
// RS = support row stride (shorts). Accumulates WITHOUT bias (caller adds after)
// to keep the hot-loop live set under 64 VGPR (8 blocks/CU).
template <int RS>
static __device__ __forceinline__ void row_gather(const unsigned short* __restrict__ supc,
                                                  const int2* __restrict__ csr_rec,
                                                  int s, int e, float a[8]) {
    if (s >= e) return;
    int2 r[4];
#pragma unroll
    for (int t = 0; t < 4; ++t) r[t] = csr_rec[min(s + t, e - 1)];
    for (int j = s; j < e; j += 4) {
        int4 sp[4];
#pragma unroll
        for (int t = 0; t < 4; ++t) sp[t] = *(const int4*)(supc + (size_t)r[t].x * RS);
        float wv[4];
#pragma unroll
        for (int t = 0; t < 4; ++t) wv[t] = (j + t < e) ? __int_as_float(r[t].y) : 0.0f;
        int jn = j + 4;
        if (jn < e) {
#pragma unroll
            for (int t = 0; t < 4; ++t) r[t] = csr_rec[min(jn + t, e - 1)];
        }
#pragma unroll
        for (int t = 0; t < 4; ++t) {
            float w = wv[t];
            int q[4] = {sp[t].x, sp[t].y, sp[t].z, sp[t].w};
#pragma unroll
            for (int c = 0; c < 4; ++c) {
                float flo = __uint_as_float(((unsigned)q[c]) << 16);
                float fhi = __uint_as_float(((unsigned)q[c]) & 0xffff0000u);
                a[2 * c]     += w * flo;
                a[2 * c + 1] += w * fhi;
            }
        }
    }
}

// ---------- MFMA GEMM (layer 1): one 64-row tile per block, A direct from global ----------
template <int K, int M, bool DYNIN>
__global__ __launch_bounds__(256, 8) void mgemm_kernel(const void* __restrict__ hv_,
                                                       const void* __restrict__ W,
                                                       unsigned short* __restrict__ out,
                                                       const int* __restrict__ flagp) {
    constexpr int KP = K + 8;
    constexpr int NC = M / 16;
    constexpr int NK = K / 32;

    __shared__ __align__(16) unsigned short wt[M][KP];  // W transposed

    const int bf = *flagp;
    const int tid = threadIdx.x;

    for (int i = tid; i < K * M; i += 256) {
        int k = i / M, m = i % M;
        wt[m][k] = f2bf(ldf(W, i, bf));
    }
    __syncthreads();

    const int lane = tid & 63;
    const int qd = lane >> 4;
    const int ln = lane & 15;
    const int wrow = (tid >> 6) * 16;
    const int tile = blockIdx.x;

    const int row = tile * 64 + wrow + ln;
    const bool ok = row < N_NODES;

    f32x4 acc[NC];
#pragma unroll
    for (int c = 0; c < NC; ++c) acc[c] = (f32x4){0.f, 0.f, 0.f, 0.f};

#pragma unroll
    for (int ks = 0; ks < NK; ++ks) {
        bf16x8 a;
        if (ok) {
            const size_t base = (size_t)row * K + ks * 32 + qd * 8;
            if (DYNIN && !bf) {
                const float* xp = (const float*)hv_ + base;
                float4 f0 = *(const float4*)xp;
                float4 f1 = *(const float4*)(xp + 4);
                ushort4 uu[2];
                uu[0].x = f2bf(f0.x); uu[0].y = f2bf(f0.y); uu[0].z = f2bf(f0.z); uu[0].w = f2bf(f0.w);
                uu[1].x = f2bf(f1.x); uu[1].y = f2bf(f1.y); uu[1].z = f2bf(f1.z); uu[1].w = f2bf(f1.w);
                a = *(const bf16x8*)uu;
            } else {
                a = *(const bf16x8*)((const unsigned short*)hv_ + base);
            }
        } else {
            a = (bf16x8)(__bf16)0.0f;
        }
#pragma unroll
        for (int c = 0; c < NC; ++c) {
            bf16x8 b = *(const bf16x8*)&wt[c * 16 + ln][ks * 32 + qd * 8];
            acc[c] = __builtin_amdgcn_mfma_f32_16x16x32_bf16(a, b, acc[c], 0, 0, 0);
        }
    }

#pragma unroll
    for (int c = 0; c < NC; ++c) {
#pragma unroll
        for (int r = 0; r < 4; ++r) {
            int orow = tile * 64 + wrow + qd * 4 + r;
            if (orow < N_NODES) out[(size_t)orow * M + c * 16 + ln] = f2bf(acc[c][r]);
        }
    }
}

// ---------- Fused: agg = relu(spmm(support)+bias); out = agg @ W  (K=64 fixed) ----------
// Gather: 32 groups x 8 lanes, 1 row per group per pass, 2 passes -> 64-row tile.
template <int MOUT>
__global__ __launch_bounds__(256, 8) void fused_kernel(const unsigned short* __restrict__ support,
                                                       const int* __restrict__ row_start,
                                                       const int2* __restrict__ csr_rec,
                                                       const void* __restrict__ bias,
                                                       const void* __restrict__ W,
                                                       unsigned short* __restrict__ out,
                                                       const int* __restrict__ flagp) {
    constexpr int K = 64, KP = 72;
    constexpr int NC = MOUT / 16;
    constexpr int NK = 2;

    __shared__ __align__(16) unsigned short agg[64][KP];
    __shared__ __align__(16) unsigned short wt[MOUT][KP];

    const int bf = *flagp;
    const int tid = threadIdx.x;

    for (int i = tid; i < K * MOUT; i += 256) {
        int k = i / MOUT, m = i % MOUT;
        wt[m][k] = f2bf(ldf(W, i, bf));
    }
    // no barrier here: gather phase doesn't read wt; W-stage latency hides under gather

    const int lane = tid & 63;
    const int qd = lane >> 4;
    const int ln = lane & 15;
    const int wrow = (tid >> 6) * 16;

    const int grp = tid >> 3;   // 32 groups of 8 lanes; 1 row each per pass
    const int cc = tid & 7;     // cols cc*8..cc*8+7
    const unsigned short* supc = support + cc * 8;

    const int tile = blockIdx.x;
    const int rowA = tile * 64 + grp;
    const int rowB = rowA + 32;
    int s0 = row_start[min(rowA, N_NODES)];
    int e0 = row_start[min(rowA + 1, N_NODES)];
    int s1 = row_start[min(rowB, N_NODES)];
    int e1 = row_start[min(rowB + 1, N_NODES)];

    {
        float a[8];
#pragma unroll
        for (int c = 0; c < 8; ++c) a[c] = 0.0f;
        row_gather<64>(supc, csr_rec, s0, e0, a);
#pragma unroll
        for (int c = 0; c < 8; ++c) a[c] = fmaxf(a[c] + ldf(bias, cc * 8 + c, bf), 0.f);
        st8_half(&agg[grp][cc * 8], a);
    }
    {
        float a[8];
#pragma unroll
        for (int c = 0; c < 8; ++c) a[c] = 0.0f;
        row_gather<64>(supc, csr_rec, s1, e1, a);
#pragma unroll
        for (int c = 0; c < 8; ++c) a[c] = fmaxf(a[c] + ldf(bias, cc * 8 + c, bf), 0.f);
        st8_half(&agg[32 + grp][cc * 8], a);
    }
    __syncthreads();

    f32x4 macc[NC];
#pragma unroll
    for (int c = 0; c < NC; ++c) macc[c] = (f32x4){0.f, 0.f, 0.f, 0.f};
#pragma unroll
    for (int ks = 0; ks < NK; ++ks) {
        bf16x8 a = *(const bf16x8*)&agg[wrow + ln][ks * 32 + qd * 8];
#pragma unroll
        for (int c = 0; c < NC; ++c) {
            bf16x8 b = *(const bf16x8*)&wt[c * 16 + ln][ks * 32 + qd * 8];
            macc[c] = __builtin_amdgcn_mfma_f32_16x16x32_bf16(a, b, macc[c], 0, 0, 0);
        }
    }

#pragma unroll
    for (int c = 0; c < NC; ++c) {
#pragma unroll
        for (int r = 0; r < 4; ++r) {
            int orow = tile * 64 + wrow + qd * 4 + r;
            if (orow < N_NODES) out[(size_t)orow * MOUT + c * 16 + ln] = f2bf(macc[c][r]);
        }
    }
}

// ---------- final SpMM (M=16): 2 lanes x 16B per row, 1 row per group, 128 rows/block ----------
template <bool DYNOUT>
__global__ __launch_bounds__(256, 8) void spmm16_kernel(const unsigned short* __restrict__ support,
                                                        const int* __restrict__ row_start,
                                                        const int2* __restrict__ csr_rec,
                                                        const void* __restrict__ bias,
                                                        void* __restrict__ out_,
                                                        const int* __restrict__ flagp) {
    constexpr int M = 16;
    int bf = *flagp;
    int tid = threadIdx.x;
    int grp = tid >> 1;           // 128 groups x 1 row = 128 rows per block
    int cc = tid & 1;             // cols cc*8..cc*8+7
    int row = blockIdx.x * 128 + grp;
    if (row >= N_NODES) return;
    int s = row_start[row];
    int e = row_start[row + 1];
    float a[8];
#pragma unroll
    for (int c = 0; c < 8; ++c) a[c] = 0.0f;
    row_gather<16>(support + cc * 8, csr_rec, s, e, a);
#pragma unroll
    for (int c = 0; c < 8; ++c) a[c] += ldf(bias, cc * 8 + c, bf);
    if (DYNOUT && !bf) {
        float* op = (float*)out_ + (size_t)row * M + cc * 8;
        *(float4*)op = make_float4(a[0], a[1], a[2], a[3]);
        *(float4*)(op + 4) = make_float4(a[4], a[5], a[6], a[7]);
    } else {
        st8_half((unsigned short*)out_ + (size_t)row * M + cc * 8, a);
    }
}

extern "C" void kernel_launch(void* const* d_in, const int* in_sizes, int n_in,
                              void* d_out, int out_size, void* d_ws, size_t ws_size,
                              hipStream_t stream) {
    (void)in_sizes; (void)n_in; (void)out_size; (void)ws_size;
    const void* x  = d_in[0];
    const void* ev = d_in[1];
    const void* W1 = d_in[2];
    const void* b1 = d_in[3];
    const void* W2 = d_in[4];
    const void* b2 = d_in[5];
    const void* W3 = d_in[6];
    const void* b3 = d_in[7];
    const int* esrc = (const int*)d_in[8];
    const int* edst = (const int*)d_in[9];

    // workspace (~34 MB)
    char* ws = (char*)d_ws;
    size_t off = 0;
    auto alloc = [&](size_t bytes) -> void* {
        void* p = ws + off;
        off = (off + bytes + 255) & ~(size_t)255;
        return p;
    };
    unsigned short* A = (unsigned short*)alloc((size_t)N_NODES * 64 * 2);  // support1 / A3
    unsigned short* B = (unsigned short*)alloc((size_t)N_NODES * 64 * 2);  // A2
    int* row_start  = (int*)alloc((size_t)(N_NODES + 1) * 4);
    int* bcursor    = (int*)alloc(1024);
    int2* csr_rec   = (int2*)alloc((size_t)N_EDGES * 8);
    int* flagp      = (int*)alloc(256);
    // part[] (10.4 MB = 196*CAP*8) aliases A (12.8 MB): dead before mgemm1 writes A
    int2* part      = (int2*)A;

    // ---- dtype probe + cursor init ----
    detect_kernel<<<1, 256, 0, stream>>>((const unsigned short*)x, flagp, bcursor);

    // ---- CSR build: partition -> place (compact, src-slab-ordered within rows) ----
    part_kernel<<<(N_EDGES + 2047) / 2048, 256, 0, stream>>>(esrc, edst, ev, bcursor, part, flagp);
    place_kernel<<<NBUCK, 512, 0, stream>>>(bcursor, part, row_start, csr_rec);

    const int NT = (N_NODES + 63) / 64;  // 1563

    // ---- layer 1: A = x @ W1 ----
    mgemm_kernel<128, 64, true><<<NT, 256, 0, stream>>>(x, W1, A, flagp);
    // ---- layer 1 agg + layer 2 gemm fused: B = relu(spmm(A)+b1) @ W2 ----
    fused_kernel<64><<<NT, 256, 0, stream>>>(A, row_start, csr_rec, b1, W2, B, flagp);
    // ---- layer 2 agg + layer 3 gemm fused: A(=A3) = relu(spmm(B)+b2) @ W3 ----
    fused_kernel<16><<<NT, 256, 0, stream>>>(B, row_start, csr_rec, b2, W3, A, flagp);
    // ---- final aggregation: out = spmm(A3) + b3 ----
    spmm16_kernel<true><<<(N_NODES + 127) / 128, 256, 0, stream>>>(A, row_start, csr_rec, b3, d_out, flagp);
}

// Round 6
// 227.953 us; speedup vs baseline: 1.3617x; 1.0030x over previous
//
#include <hip/hip_runtime.h>
#include <stdint.h>

#define N_NODES 100000
#define N_EDGES 1000000
#define NBUCK 196   // ceil(N_NODES / 512)
#define CAP 6656    // per-bucket part capacity; counts ~ Poisson(5120), +21 sigma

typedef __attribute__((ext_vector_type(8))) __bf16 bf16x8;
typedef __attribute__((ext_vector_type(4))) float f32x4;

// ---------- bf16 helpers ----------
static __device__ __forceinline__ float bf2f(unsigned short u) {
    return __uint_as_float(((unsigned int)u) << 16);
}
static __device__ __forceinline__ unsigned short f2bf(float f) {
    unsigned int u = __float_as_uint(f);
    unsigned int r = (u + 0x7FFFu + ((u >> 16) & 1u)) >> 16;  // RNE
    return (unsigned short)r;
}
// pack 8 f32 -> 8 bf16, one 16B store
static __device__ __forceinline__ void st8_half(unsigned short* p, const float* f) {
    int4 u;
    u.x = (int)(((unsigned)f2bf(f[0])) | (((unsigned)f2bf(f[1])) << 16));
    u.y = (int)(((unsigned)f2bf(f[2])) | (((unsigned)f2bf(f[3])) << 16));
    u.z = (int)(((unsigned)f2bf(f[4])) | (((unsigned)f2bf(f[5])) << 16));
    u.w = (int)(((unsigned)f2bf(f[6])) | (((unsigned)f2bf(f[7])) << 16));
    *(int4*)p = u;
}

// ---------- dynamic-dtype external loads (flag: 1 = bf16 memory, 0 = f32) ----------
static __device__ __forceinline__ float ldf(const void* p, size_t i, int bf) {
    return bf ? bf2f(((const unsigned short*)p)[i]) : ((const float*)p)[i];
}

// ---------- dtype probe + cursor init ----------
__global__ __launch_bounds__(256) void detect_kernel(const unsigned short* __restrict__ xs,
                                                     int* __restrict__ flag,
                                                     int* __restrict__ bcursor) {
    __shared__ int sz;
    if (threadIdx.x == 0) sz = 0;
    __syncthreads();
    int z = 0;
    for (int i = threadIdx.x; i < 1024; i += 256) {
        float av = fabsf(bf2f(xs[2 * i]));
        if (!(av <= 1048576.0f) || (av != 0.0f && av < 9.5367431640625e-07f)) z++;
    }
    atomicAdd(&sz, z);
    if (threadIdx.x < NBUCK) bcursor[threadIdx.x] = threadIdx.x * CAP;
    __syncthreads();
    if (threadIdx.x == 0) *flag = (sz > 256) ? 0 : 1;
}

// ---------- partition edges into fixed-capacity bucket regions ----------
// Block-local counting sort by bucket (dst>>9) in LDS, then bucket-contiguous
// (coalesced-run) global writes. rec = {src | dst_local<<17, val_bits}.
__global__ __launch_bounds__(256) void part_kernel(const int* __restrict__ src,
                                                   const int* __restrict__ dst,
                                                   const void* __restrict__ val,
                                                   int* __restrict__ bcursor,
                                                   int2* __restrict__ part,
                                                   const int* __restrict__ flagp) {
    __shared__ int cnt[256];           // per-bucket counts (196 used)
    __shared__ int s[256];             // inclusive prefix of cnt
    __shared__ int base[NBUCK];        // global base per bucket
    __shared__ int2 stage[2048];       // bucket-sorted records
    __shared__ unsigned char bktl[2048];
    const int bf = *flagp;
    const int tid = threadIdx.x;
    const int e0 = blockIdx.x * 2048;
    cnt[tid] = 0;
    __syncthreads();
    int rank[8], bkt[8], pk[8], vb[8];
#pragma unroll
    for (int i = 0; i < 8; ++i) {
        int e = e0 + i * 256 + tid;
        bkt[i] = -1;
        if (e < N_EDGES) {
            int d = dst[e];
            int b = d >> 9;
            bkt[i] = b;
            pk[i] = src[e] | ((d & 511) << 17);
            vb[i] = __float_as_int(ldf(val, e, bf));
            rank[i] = atomicAdd(&cnt[b], 1);
        }
    }
    __syncthreads();
    // inclusive prefix scan of cnt over 256 entries
    s[tid] = cnt[tid];
    __syncthreads();
    for (int off = 1; off < 256; off <<= 1) {
        int t = 0;
        if (tid >= off) t = s[tid - off];
        __syncthreads();
        if (tid >= off) s[tid] += t;
        __syncthreads();
    }
    // global bases + local bucket-sorted staging
    for (int i = tid; i < NBUCK; i += 256) {
        int c = cnt[i];
        base[i] = c ? atomicAdd(&bcursor[i], c) : 0;
    }
#pragma unroll
    for (int i = 0; i < 8; ++i) {
        if (bkt[i] >= 0) {
            int b = bkt[i];
            int sp = s[b] - cnt[b] + rank[i];   // block-local sorted position
            stage[sp] = make_int2(pk[i], vb[i]);
            bktl[sp] = (unsigned char)b;
        }
    }
    __syncthreads();
    // coalesced-run writeout: consecutive j in same bucket -> consecutive global
    const int nE = min(2048, N_EDGES - e0);
    for (int j = tid; j < nE; j += 256) {
        int bk = bktl[j];
        part[(size_t)base[bk] + (j - (s[bk] - cnt[bk]))] = stage[j];
    }
}

// ---------- place: per-bucket (512 rows) histogram+scan, compact csr_rec + row_start ----------
// Each block redundantly prefix-scans the 196 bucket counts (from bcursor) itself.
__global__ __launch_bounds__(512) void place_kernel(const int* __restrict__ bcursor,
                                                    const int2* __restrict__ part,
                                                    int* __restrict__ row_start,
                                                    int2* __restrict__ csr_rec) {
    __shared__ int cnt[512];
    __shared__ int sums[512];
    __shared__ int sh_s, sh_cnt, sh_total;
    const int tid = threadIdx.x;
    const int b = blockIdx.x;
    const int row0 = b << 9;
    const int nrows = min(512, N_NODES - row0);

    // bucket-count exclusive prefix over 196 buckets (redundant per block, trivial)
    if (tid < 256) sums[tid] = (tid < NBUCK) ? (bcursor[tid] - tid * CAP) : 0;
    __syncthreads();
    for (int off = 1; off < 256; off <<= 1) {
        int t = 0;
        if (tid < 256 && tid >= off) t = sums[tid - off];
        __syncthreads();
        if (tid < 256 && tid >= off) sums[tid] += t;
        __syncthreads();
    }
    if (tid == 0) {
        sh_s = (b > 0) ? sums[b - 1] : 0;
        sh_cnt = bcursor[b] - b * CAP;
        sh_total = sums[NBUCK - 1];
    }
    __syncthreads();
    const int s = sh_s;          // global csr_rec start of this bucket
    const int cb = sh_cnt;       // edges in this bucket
    const int ps = b * CAP;      // part region start
    const int total = sh_total;

    cnt[tid] = 0;
    __syncthreads();
    for (int j = tid; j < cb; j += 512) {
        unsigned p = (unsigned)part[ps + j].x;
        atomicAdd(&cnt[p >> 17], 1);
    }
    __syncthreads();
    int own = cnt[tid];
    sums[tid] = own;
    __syncthreads();
    for (int off = 1; off < 512; off <<= 1) {
        int t = 0;
        if (tid >= off) t = sums[tid - off];
        __syncthreads();
        if (tid >= off) sums[tid] += t;
        __syncthreads();
    }
    int excl = sums[tid] - own;
    cnt[tid] = s + excl;              // running cursor (global position)
    if (tid < nrows) row_start[row0 + tid] = s + excl;
    if (b == NBUCK - 1 && tid == 0) row_start[N_NODES] = total;
    __syncthreads();
    for (int j = tid; j < cb; j += 512) {
        int2 r = part[ps + j];
        unsigned p = (unsigned)r.x;
        int pos = atomicAdd(&cnt[p >> 17], 1);
        csr_rec[pos] = make_int2((int)(p & 0x1FFFFu), r.y);
    }
}

// ---------- single-row gather: 8 bf16 cols per lane, chunk of 4 edges ----------
// RS = support row stride (shorts). Accumulates WITHOUT bias (caller adds after)
// to keep the hot-loop live set under 64 VGPR (8 blocks/CU).
template <int RS>
static __device__ __forceinline__ void row_gather(const unsigned short* __restrict__ supc,
                                                  const int2* __restrict__ csr_rec,
                                                  int s, int e, float a[8]) {
    if (s >= e) return;
    int2 r[4];
#pragma unroll
    for (int t = 0; t < 4; ++t) r[t] = csr_rec[min(s + t, e - 1)];
    for (int j = s; j < e; j += 4) {
        int4 sp[4];
#pragma unroll
        for (int t = 0; t < 4; ++t) sp[t] = *(const int4*)(supc + (size_t)r[t].x * RS);
        float wv[4];
#pragma unroll
        for (int t = 0; t < 4; ++t) wv[t] = (j + t < e) ? __int_as_float(r[t].y) : 0.0f;
        int jn = j + 4;
        if (jn < e) {
#pragma unroll
            for (int t = 0; t < 4; ++t) r[t] = csr_rec[min(jn + t, e - 1)];
        }
#pragma unroll
        for (int t = 0; t < 4; ++t) {
            float w = wv[t];
            int q[4] = {sp[t].x, sp[t].y, sp[t].z, sp[t].w};
#pragma unroll
            for (int c = 0; c < 4; ++c) {
                float flo = __uint_as_float(((unsigned)q[c]) << 16);
                float fhi = __uint_as_float(((unsigned)q[c]) & 0xffff0000u);
                a[2 * c]     += w * flo;
                a[2 * c + 1] += w * fhi;
            }
        }
    }
}

// ---------- MFMA GEMM (layer 1): one 64-row tile per block, A direct from global ----------
template <int K, int M, bool DYNIN>
__global__ __launch_bounds__(256, 8) void mgemm_kernel(const void* __restrict__ hv_,
                                                       const void* __restrict__ W,
                                                       unsigned short* __restrict__ out,
                                                       const int* __restrict__ flagp) {
    constexpr int KP = K + 8;
    constexpr int NC = M / 16;
    constexpr int NK = K / 32;

    __shared__ __align__(16) unsigned short wt[M][KP];  // W transposed

    const int bf = *flagp;
    const int tid = threadIdx.x;

    for (int i = tid; i < K * M; i += 256) {
        int k = i / M, m = i % M;
        wt[m][k] = f2bf(ldf(W, i, bf));
    }
    __syncthreads();

    const int lane = tid & 63;
    const int qd = lane >> 4;
    const int ln = lane & 15;
    const int wrow = (tid >> 6) * 16;
    const int tile = blockIdx.x;

    const int row = tile * 64 + wrow + ln;
    const bool ok = row < N_NODES;

    f32x4 acc[NC];
#pragma unroll
    for (int c = 0; c < NC; ++c) acc[c] = (f32x4){0.f, 0.f, 0.f, 0.f};

#pragma unroll
    for (int ks = 0; ks < NK; ++ks) {
        bf16x8 a;
        if (ok) {
            const size_t base = (size_t)row * K + ks * 32 + qd * 8;
            if (DYNIN && !bf) {
                const float* xp = (const float*)hv_ + base;
                float4 f0 = *(const float4*)xp;
                float4 f1 = *(const float4*)(xp + 4);
                ushort4 uu[2];
                uu[0].x = f2bf(f0.x); uu[0].y = f2bf(f0.y); uu[0].z = f2bf(f0.z); uu[0].w = f2bf(f0.w);
                uu[1].x = f2bf(f1.x); uu[1].y = f2bf(f1.y); uu[1].z = f2bf(f1.z); uu[1].w = f2bf(f1.w);
                a = *(const bf16x8*)uu;
            } else {
                a = *(const bf16x8*)((const unsigned short*)hv_ + base);
            }
        } else {
            a = (bf16x8)(__bf16)0.0f;
        }
#pragma unroll
        for (int c = 0; c < NC; ++c) {
            bf16x8 b = *(const bf16x8*)&wt[c * 16 + ln][ks * 32 + qd * 8];
            acc[c] = __builtin_amdgcn_mfma_f32_16x16x32_bf16(a, b, acc[c], 0, 0, 0);
        }
    }

#pragma unroll
    for (int c = 0; c < NC; ++c) {
#pragma unroll
        for (int r = 0; r < 4; ++r) {
            int orow = tile * 64 + wrow + qd * 4 + r;
            if (orow < N_NODES) out[(size_t)orow * M + c * 16 + ln] = f2bf(acc[c][r]);
        }
    }
}

// ---------- Fused: agg = relu(spmm(support)+bias); out = agg @ W  (K=64 fixed) ----------
// Gather: 32 groups x 8 lanes, 1 row per group per pass, 2 passes -> 64-row tile.
template <int MOUT>
__global__ __launch_bounds__(256, 8) void fused_kernel(const unsigned short* __restrict__ support,
                                                       const int* __restrict__ row_start,
                                                       const int2* __restrict__ csr_rec,
                                                       const void* __restrict__ bias,
                                                       const void* __restrict__ W,
                                                       unsigned short* __restrict__ out,
                                                       const int* __restrict__ flagp) {
    constexpr int K = 64, KP = 72;
    constexpr int NC = MOUT / 16;
    constexpr int NK = 2;

    __shared__ __align__(16) unsigned short agg[64][KP];
    __shared__ __align__(16) unsigned short wt[MOUT][KP];

    const int bf = *flagp;
    const int tid = threadIdx.x;

    for (int i = tid; i < K * MOUT; i += 256) {
        int k = i / MOUT, m = i % MOUT;
        wt[m][k] = f2bf(ldf(W, i, bf));
    }
    // no barrier here: gather phase doesn't read wt; W-stage latency hides under gather

    const int lane = tid & 63;
    const int qd = lane >> 4;
    const int ln = lane & 15;
    const int wrow = (tid >> 6) * 16;

    const int grp = tid >> 3;   // 32 groups of 8 lanes; 1 row each per pass
    const int cc = tid & 7;     // cols cc*8..cc*8+7
    const unsigned short* supc = support + cc * 8;

    const int tile = blockIdx.x;
    const int rowA = tile * 64 + grp;
    const int rowB = rowA + 32;
    int s0 = row_start[min(rowA, N_NODES)];
    int e0 = row_start[min(rowA + 1, N_NODES)];
    int s1 = row_start[min(rowB, N_NODES)];
    int e1 = row_start[min(rowB + 1, N_NODES)];

    {
        float a[8];
#pragma unroll
        for (int c = 0; c < 8; ++c) a[c] = 0.0f;
        row_gather<64>(supc, csr_rec, s0, e0, a);
#pragma unroll
        for (int c = 0; c < 8; ++c) a[c] = fmaxf(a[c] + ldf(bias, cc * 8 + c, bf), 0.f);
        st8_half(&agg[grp][cc * 8], a);
    }
    {
        float a[8];
#pragma unroll
        for (int c = 0; c < 8; ++c) a[c] = 0.0f;
        row_gather<64>(supc, csr_rec, s1, e1, a);
#pragma unroll
        for (int c = 0; c < 8; ++c) a[c] = fmaxf(a[c] + ldf(bias, cc * 8 + c, bf), 0.f);
        st8_half(&agg[32 + grp][cc * 8], a);
    }
    __syncthreads();

    f32x4 macc[NC];
#pragma unroll
    for (int c = 0; c < NC; ++c) macc[c] = (f32x4){0.f, 0.f, 0.f, 0.f};
#pragma unroll
    for (int ks = 0; ks < NK; ++ks) {
        bf16x8 a = *(const bf16x8*)&agg[wrow + ln][ks * 32 + qd * 8];
#pragma unroll
        for (int c = 0; c < NC; ++c) {
            bf16x8 b = *(const bf16x8*)&wt[c * 16 + ln][ks * 32 + qd * 8];
            macc[c] = __builtin_amdgcn_mfma_f32_16x16x32_bf16(a, b, macc[c], 0, 0, 0);
        }
    }

#pragma unroll
    for (int c = 0; c < NC; ++c) {
#pragma unroll
        for (int r = 0; r < 4; ++r) {
            int orow = tile * 64 + wrow + qd * 4 + r;
            if (orow < N_NODES) out[(size_t)orow * MOUT + c * 16 + ln] = f2bf(macc[c][r]);
        }
    }
}

// ---------- final SpMM (M=16): 2 lanes x 16B per row, 1 row per group, 128 rows/block ----------
template <bool DYNOUT>
__global__ __launch_bounds__(256, 8) void spmm16_kernel(const unsigned short* __restrict__ support,
                                                        const int* __restrict__ row_start,
                                                        const int2* __restrict__ csr_rec,
                                                        const void* __restrict__ bias,
                                                        void* __restrict__ out_,
                                                        const int* __restrict__ flagp) {
    constexpr int M = 16;
    int bf = *flagp;
    int tid = threadIdx.x;
    int grp = tid >> 1;           // 128 groups x 1 row = 128 rows per block
    int cc = tid & 1;             // cols cc*8..cc*8+7
    int row = blockIdx.x * 128 + grp;
    if (row >= N_NODES) return;
    int s = row_start[row];
    int e = row_start[row + 1];
    float a[8];
#pragma unroll
    for (int c = 0; c < 8; ++c) a[c] = 0.0f;
    row_gather<16>(support + cc * 8, csr_rec, s, e, a);
#pragma unroll
    for (int c = 0; c < 8; ++c) a[c] += ldf(bias, cc * 8 + c, bf);
    if (DYNOUT && !bf) {
        float* op = (float*)out_ + (size_t)row * M + cc * 8;
        *(float4*)op = make_float4(a[0], a[1], a[2], a[3]);
        *(float4*)(op + 4) = make_float4(a[4], a[5], a[6], a[7]);
    } else {
        st8_half((unsigned short*)out_ + (size_t)row * M + cc * 8, a);
    }
}

extern "C" void kernel_launch(void* const* d_in, const int* in_sizes, int n_in,
                              void* d_out, int out_size, void* d_ws, size_t ws_size,
                              hipStream_t stream) {
    (void)in_sizes; (void)n_in; (void)out_size; (void)ws_size;
    const void* x  = d_in[0];
    const void* ev = d_in[1];
    const void* W1 = d_in[2];
    const void* b1 = d_in[3];
    const void* W2 = d_in[4];
    const void* b2 = d_in[5];
    const void* W3 = d_in[6];
    const void* b3 = d_in[7];
    const int* esrc = (const int*)d_in[8];
    const int* edst = (const int*)d_in[9];

    // workspace (~34 MB)
    char* ws = (char*)d_ws;
    size_t off = 0;
    auto alloc = [&](size_t bytes) -> void* {
        void* p = ws + off;
        off = (off + bytes + 255) & ~(size_t)255;
        return p;
    };
    unsigned short* A = (unsigned short*)alloc((size_t)N_NODES * 64 * 2);  // support1 / A3
    unsigned short* B = (unsigned short*)alloc((size_t)N_NODES * 64 * 2);  // A2
    int* row_start  = (int*)alloc((size_t)(N_NODES + 1) * 4);
    int* bcursor    = (int*)alloc(1024);
    int2* csr_rec   = (int2*)alloc((size_t)N_EDGES * 8);
    int* flagp      = (int*)alloc(256);
    // part[] (10.4 MB = 196*CAP*8) aliases A (12.8 MB): dead before mgemm1 writes A
    int2* part      = (int2*)A;

    // ---- dtype probe + cursor init ----
    detect_kernel<<<1, 256, 0, stream>>>((const unsigned short*)x, flagp, bcursor);

    // ---- CSR build: partition (LDS counting sort) -> place (compact) ----
    part_kernel<<<(N_EDGES + 2047) / 2048, 256, 0, stream>>>(esrc, edst, ev, bcursor, part, flagp);
    place_kernel<<<NBUCK, 512, 0, stream>>>(bcursor, part, row_start, csr_rec);

    const int NT = (N_NODES + 63) / 64;  // 1563

    // ---- layer 1: A = x @ W1 ----
    mgemm_kernel<128, 64, true><<<NT, 256, 0, stream>>>(x, W1, A, flagp);
    // ---- layer 1 agg + layer 2 gemm fused: B = relu(spmm(A)+b1) @ W2 ----
    fused_kernel<64><<<NT, 256, 0, stream>>>(A, row_start, csr_rec, b1, W2, B, flagp);
    // ---- layer 2 agg + layer 3 gemm fused: A(=A3) = relu(spmm(B)+b2) @ W3 ----
    fused_kernel<16><<<NT, 256, 0, stream>>>(B, row_start, csr_rec, b2, W3, A, flagp);
    // ---- final aggregation: out = spmm(A3) + b3 ----
    spmm16_kernel<true><<<(N_NODES + 127) / 128, 256, 0, stream>>>(A, row_start, csr_rec, b3, d_out, flagp);
}